// Round 1
// baseline (407.183 us; speedup 1.0000x reference)
//
#include <hip/hip_runtime.h>

#define BB 4
#define CC 32
#define HH 512
#define WW 512
#define HWSZ (HH * WW)
#define PLANE ((size_t)HH * WW)
#define NPIX ((size_t)BB * HH * WW)

// ---------------------------------------------------------------------------
// Kernel A: compute off_x, off_y = conv3x3(x, w_off[0:2]) + b_off[0:2]
// 16x16 pixel tile per block, loop over 32 input channels, LDS-staged halo.
// ---------------------------------------------------------------------------
__global__ __launch_bounds__(256) void conv_off_kernel(
    const float* __restrict__ x, const float* __restrict__ w_off,
    const float* __restrict__ b_off, float* __restrict__ off) {
  __shared__ float tile[18][19];   // +1 pad to break bank stride
  __shared__ float wl[576];        // w_off channels 0,1 : 2*32*9 floats

  const int tx = threadIdx.x & 15;
  const int ty = threadIdx.x >> 4;
  const int bw = blockIdx.x * 16;
  const int bh = blockIdx.y * 16;
  const int b  = blockIdx.z;

  // w_off layout (18,32,3,3): co=0 occupies [0,288), co=1 occupies [288,576)
  for (int i = threadIdx.x; i < 576; i += 256) wl[i] = w_off[i];

  float acc0 = b_off[0];
  float acc1 = b_off[1];

  const float* xb = x + (size_t)b * CC * PLANE;

  for (int ci = 0; ci < CC; ++ci) {
    const float* xp = xb + (size_t)ci * PLANE;
    // stage 18x18 halo tile starting at (bh-1, bw-1), zero-padded
    for (int i = threadIdx.x; i < 18 * 18; i += 256) {
      int r = i / 18;
      int c = i - r * 18;
      int gy = bh - 1 + r;
      int gx = bw - 1 + c;
      float v = 0.f;
      if (gy >= 0 && gy < HH && gx >= 0 && gx < WW) v = xp[gy * WW + gx];
      tile[r][c] = v;
    }
    __syncthreads();

    const float* w0 = &wl[ci * 9];
    const float* w1 = &wl[288 + ci * 9];
#pragma unroll
    for (int kh = 0; kh < 3; ++kh) {
#pragma unroll
      for (int kw = 0; kw < 3; ++kw) {
        float v = tile[ty + kh][tx + kw];
        acc0 += v * w0[kh * 3 + kw];
        acc1 += v * w1[kh * 3 + kw];
      }
    }
    __syncthreads();
  }

  const int h = bh + ty;
  const int w = bw + tx;
  const size_t idx = ((size_t)b * HH + h) * WW + w;
  off[idx] = acc0;          // off_x (channel 0)
  off[NPIX + idx] = acc1;   // off_y (channel 1)
}

// ---------------------------------------------------------------------------
// Kernel B: bilinear zero-padded sample of all 32 channels at (w+offx, h+offy)
// One thread per pixel; channel loop inside. Writes coalesced along w.
// ---------------------------------------------------------------------------
__global__ __launch_bounds__(256) void sample_kernel(
    const float* __restrict__ x, const float* __restrict__ off,
    float* __restrict__ out) {
  const size_t tid = (size_t)blockIdx.x * 256 + threadIdx.x;
  const int w = (int)(tid & (WW - 1));
  const int h = (int)((tid >> 9) & (HH - 1));
  const int b = (int)(tid >> 18);

  const float off_x = off[tid];
  const float off_y = off[NPIX + tid];

  const float ix = (float)w + off_x;
  const float iy = (float)h + off_y;

  const float x0f = floorf(ix);
  const float y0f = floorf(iy);
  const float x1f = x0f + 1.f;
  const float y1f = y0f + 1.f;

  const float wx1 = ix - x0f;
  const float wx0 = 1.f - wx1;
  const float wy1 = iy - y0f;
  const float wy0 = 1.f - wy1;

  const bool vx0 = (x0f >= 0.f) && (x0f <= (float)(WW - 1));
  const bool vx1 = (x1f >= 0.f) && (x1f <= (float)(WW - 1));
  const bool vy0 = (y0f >= 0.f) && (y0f <= (float)(HH - 1));
  const bool vy1 = (y1f >= 0.f) && (y1f <= (float)(HH - 1));

  const int xi0 = (int)fminf(fmaxf(x0f, 0.f), (float)(WW - 1));
  const int xi1 = (int)fminf(fmaxf(x1f, 0.f), (float)(WW - 1));
  const int yi0 = (int)fminf(fmaxf(y0f, 0.f), (float)(HH - 1));
  const int yi1 = (int)fminf(fmaxf(y1f, 0.f), (float)(HH - 1));

  const float w00 = wy0 * wx0 * ((vy0 && vx0) ? 1.f : 0.f);
  const float w01 = wy0 * wx1 * ((vy0 && vx1) ? 1.f : 0.f);
  const float w10 = wy1 * wx0 * ((vy1 && vx0) ? 1.f : 0.f);
  const float w11 = wy1 * wx1 * ((vy1 && vx1) ? 1.f : 0.f);

  const int i00 = yi0 * WW + xi0;
  const int i01 = yi0 * WW + xi1;
  const int i10 = yi1 * WW + xi0;
  const int i11 = yi1 * WW + xi1;

  const float* xb = x + (size_t)b * CC * PLANE;
  float* ob = out + (size_t)b * CC * PLANE + (size_t)h * WW + w;

#pragma unroll 4
  for (int c = 0; c < CC; ++c) {
    const float* xp = xb + (size_t)c * PLANE;
    float v = w00 * xp[i00] + w01 * xp[i01] + w10 * xp[i10] + w11 * xp[i11];
    ob[(size_t)c * PLANE] = v;
  }
}

extern "C" void kernel_launch(void* const* d_in, const int* in_sizes, int n_in,
                              void* d_out, int out_size, void* d_ws, size_t ws_size,
                              hipStream_t stream) {
  const float* x     = (const float*)d_in[0];
  const float* w_off = (const float*)d_in[1];
  const float* b_off = (const float*)d_in[2];
  float* out = (float*)d_out;
  float* off = (float*)d_ws;  // 2 * B*H*W floats = 8 MB

  dim3 gridA(WW / 16, HH / 16, BB);
  conv_off_kernel<<<gridA, 256, 0, stream>>>(x, w_off, b_off, off);

  const int nblk = (int)(NPIX / 256);
  sample_kernel<<<nblk, 256, 0, stream>>>(x, off, out);
}

// Round 2
// 351.905 us; speedup vs baseline: 1.1571x; 1.1571x over previous
//
#include <hip/hip_runtime.h>

#define BB 4
#define CC 32
#define HH 512
#define WW 512
#define PLANE ((size_t)HH * WW)
#define NPIX ((size_t)BB * HH * WW)

// ---------------------------------------------------------------------------
// Kernel A: off_x/off_y = conv3x3(x, w_off[0:2]) + b_off[0:2].
// No LDS, no barriers. Each thread: 4 consecutive w-pixels. Per channel/row:
// one aligned float4 + 2 edge scalars; weights are loop-uniform -> SGPRs.
// Block: 256 threads = 2 rows x 128 threads (x4 px). Grid: (1, 256, 4).
// ---------------------------------------------------------------------------
__global__ __launch_bounds__(256) void conv_off_kernel(
    const float* __restrict__ x, const float* __restrict__ w_off,
    const float* __restrict__ b_off, float* __restrict__ off) {
  const int t  = threadIdx.x;
  const int w4 = (t & 127) << 2;               // 0..508
  const int h  = blockIdx.y * 2 + (t >> 7);    // 0..511
  const int b  = blockIdx.z;

  float4 acc0, acc1;
  {
    const float b0 = b_off[0], b1 = b_off[1];
    acc0.x = acc0.y = acc0.z = acc0.w = b0;
    acc1.x = acc1.y = acc1.z = acc1.w = b1;
  }

  const float* xr = x + (size_t)b * CC * PLANE + (size_t)h * WW + w4;
  const float* wp0 = w_off;          // co=0: [ci][kh][kw], 9 per channel
  const float* wp1 = w_off + 288;    // co=1

  for (int ci = 0; ci < CC; ++ci) {
#pragma unroll
    for (int kh = 0; kh < 3; ++kh) {
      const int hy = h + kh - 1;
      float vl, v0, v1, v2, v3, vr;
      if (hy >= 0 && hy < HH) {
        const float* p = xr + (ptrdiff_t)(kh - 1) * WW;
        const float4 m = *(const float4*)p;    // 16B aligned (w4 % 4 == 0)
        vl = (w4 > 0) ? p[-1] : 0.f;
        vr = (w4 < WW - 4) ? p[4] : 0.f;
        v0 = m.x; v1 = m.y; v2 = m.z; v3 = m.w;
      } else {
        vl = v0 = v1 = v2 = v3 = vr = 0.f;
      }
      const float a0 = wp0[kh * 3 + 0], a1 = wp0[kh * 3 + 1], a2 = wp0[kh * 3 + 2];
      const float c0 = wp1[kh * 3 + 0], c1 = wp1[kh * 3 + 1], c2 = wp1[kh * 3 + 2];
      acc0.x += vl * a0 + v0 * a1 + v1 * a2;
      acc0.y += v0 * a0 + v1 * a1 + v2 * a2;
      acc0.z += v1 * a0 + v2 * a1 + v3 * a2;
      acc0.w += v2 * a0 + v3 * a1 + vr * a2;
      acc1.x += vl * c0 + v0 * c1 + v1 * c2;
      acc1.y += v0 * c0 + v1 * c1 + v2 * c2;
      acc1.z += v1 * c0 + v2 * c1 + v3 * c2;
      acc1.w += v2 * c0 + v3 * c1 + vr * c2;
    }
    wp0 += 9;
    wp1 += 9;
    xr += PLANE;
  }

  const size_t idx = ((size_t)b * HH + h) * WW + w4;
  *(float4*)(off + idx) = acc0;          // off_x
  *(float4*)(off + NPIX + idx) = acc1;   // off_y
}

// ---------------------------------------------------------------------------
// Kernel B: bilinear zero-padded sample of 32 channels at (w+offx, h+offy).
// One thread per pixel. Nontemporal stores (write-once 128 MB) keep L2/L3
// free for the x gather, which is L3-resident from kernel A.
// ---------------------------------------------------------------------------
__global__ __launch_bounds__(256) void sample_kernel(
    const float* __restrict__ x, const float* __restrict__ off,
    float* __restrict__ out) {
  const size_t tid = (size_t)blockIdx.x * 256 + threadIdx.x;
  const int w = (int)(tid & (WW - 1));
  const int h = (int)((tid >> 9) & (HH - 1));
  const int b = (int)(tid >> 18);

  const float ix = (float)w + off[tid];
  const float iy = (float)h + off[NPIX + tid];

  const float x0f = floorf(ix);
  const float y0f = floorf(iy);

  const float wx1 = ix - x0f;
  const float wx0 = 1.f - wx1;
  const float wy1 = iy - y0f;
  const float wy0 = 1.f - wy1;

  const bool vx0 = (x0f >= 0.f) && (x0f <= (float)(WW - 1));
  const bool vx1 = (x0f + 1.f >= 0.f) && (x0f + 1.f <= (float)(WW - 1));
  const bool vy0 = (y0f >= 0.f) && (y0f <= (float)(HH - 1));
  const bool vy1 = (y0f + 1.f >= 0.f) && (y0f + 1.f <= (float)(HH - 1));

  const int xi0 = (int)fminf(fmaxf(x0f, 0.f), (float)(WW - 1));
  const int xi1 = (int)fminf(fmaxf(x0f + 1.f, 0.f), (float)(WW - 1));
  const int yi0 = (int)fminf(fmaxf(y0f, 0.f), (float)(HH - 1));
  const int yi1 = (int)fminf(fmaxf(y0f + 1.f, 0.f), (float)(HH - 1));

  const float w00 = wy0 * wx0 * ((vy0 && vx0) ? 1.f : 0.f);
  const float w01 = wy0 * wx1 * ((vy0 && vx1) ? 1.f : 0.f);
  const float w10 = wy1 * wx0 * ((vy1 && vx0) ? 1.f : 0.f);
  const float w11 = wy1 * wx1 * ((vy1 && vx1) ? 1.f : 0.f);

  const int i00 = yi0 * WW + xi0;
  const int i01 = yi0 * WW + xi1;
  const int i10 = yi1 * WW + xi0;
  const int i11 = yi1 * WW + xi1;

  const float* xp = x + (size_t)b * CC * PLANE;
  float* ob = out + (size_t)b * CC * PLANE + (size_t)h * WW + w;

#pragma unroll 8
  for (int c = 0; c < CC; ++c) {
    const float v = w00 * xp[i00] + w01 * xp[i01] + w10 * xp[i10] + w11 * xp[i11];
    __builtin_nontemporal_store(v, ob);
    xp += PLANE;
    ob += PLANE;
  }
}

extern "C" void kernel_launch(void* const* d_in, const int* in_sizes, int n_in,
                              void* d_out, int out_size, void* d_ws, size_t ws_size,
                              hipStream_t stream) {
  const float* x     = (const float*)d_in[0];
  const float* w_off = (const float*)d_in[1];
  const float* b_off = (const float*)d_in[2];
  float* out = (float*)d_out;
  float* off = (float*)d_ws;  // 2 * B*H*W floats = 8 MB

  dim3 gridA(1, HH / 2, BB);
  conv_off_kernel<<<gridA, 256, 0, stream>>>(x, w_off, b_off, off);

  const int nblk = (int)(NPIX / 256);
  sample_kernel<<<nblk, 256, 0, stream>>>(x, off, out);
}

// Round 3
// 340.461 us; speedup vs baseline: 1.1960x; 1.0336x over previous
//
#include <hip/hip_runtime.h>

#define BB 4
#define CC 32
#define HH 512
#define WW 512
#define PLANE ((size_t)HH * WW)
#define NPIX ((size_t)BB * HH * WW)

// ---------------------------------------------------------------------------
// Kernel A: off_x/off_y = conv3x3(x, w_off[0:2]) + b_off[0:2].
// No LDS/barriers. Thread: 4 w-px (float4) x 2 h-rows. Block: 512w x 4 rows.
// Grid: 512 blocks, XCD-band swizzled so each XCD owns 256 contiguous rows
// (per-channel band = 512 KB, fits 4 MB per-XCD L2 -> halo rows are L2 hits).
// ---------------------------------------------------------------------------
__global__ __launch_bounds__(256) void conv_off_kernel(
    const float* __restrict__ x, const float* __restrict__ w_off,
    const float* __restrict__ b_off, float* __restrict__ off) {
  const int nb = gridDim.x;                       // 512
  const int i  = blockIdx.x;
  const int j  = (i & 7) * (nb >> 3) + (i >> 3);  // XCD band swizzle
  const int b    = j >> 7;                        // 128 row-quads per batch
  const int row0 = (j & 127) << 2;

  const int t  = threadIdx.x;
  const int w4 = (t & 127) << 2;                  // 0..508
  const int h0 = row0 + ((t >> 7) << 1);          // this thread: rows h0, h0+1

  float4 a0v, a1v, b0v, b1v;                      // acc[out_row][out_ch]
  {
    const float b0 = b_off[0], b1 = b_off[1];
    a0v.x = a0v.y = a0v.z = a0v.w = b0;  b0v = a0v;   // ch0: rows h0, h0+1
    a1v.x = a1v.y = a1v.z = a1v.w = b1;  b1v = a1v;   // ch1: rows h0, h0+1
  }

  const float* xb = x + (size_t)b * CC * PLANE + (size_t)h0 * WW + w4;
  const float* wp0 = w_off;          // co=0: [ci][kh][kw]
  const float* wp1 = w_off + 288;    // co=1

  for (int ci = 0; ci < CC; ++ci) {
    float vl[4], vr[4], v0[4], v1[4], v2[4], v3[4];
#pragma unroll
    for (int r = 0; r < 4; ++r) {                 // rows h0-1 .. h0+2
      const int hy = h0 - 1 + r;
      if (hy >= 0 && hy < HH) {
        const float* p = xb + (ptrdiff_t)(r - 1) * WW;
        const float4 m = *(const float4*)p;
        vl[r] = (w4 > 0) ? p[-1] : 0.f;
        vr[r] = (w4 < WW - 4) ? p[4] : 0.f;
        v0[r] = m.x; v1[r] = m.y; v2[r] = m.z; v3[r] = m.w;
      } else {
        vl[r] = vr[r] = v0[r] = v1[r] = v2[r] = v3[r] = 0.f;
      }
    }
#pragma unroll
    for (int kh = 0; kh < 3; ++kh) {
      const float a0 = wp0[kh * 3 + 0], a1 = wp0[kh * 3 + 1], a2 = wp0[kh * 3 + 2];
      const float c0 = wp1[kh * 3 + 0], c1 = wp1[kh * 3 + 1], c2 = wp1[kh * 3 + 2];
      {  // out row h0 uses input rows kh (index kh in 0..2)
        const int r = kh;
        a0v.x += vl[r] * a0 + v0[r] * a1 + v1[r] * a2;
        a0v.y += v0[r] * a0 + v1[r] * a1 + v2[r] * a2;
        a0v.z += v1[r] * a0 + v2[r] * a1 + v3[r] * a2;
        a0v.w += v2[r] * a0 + v3[r] * a1 + vr[r] * a2;
        a1v.x += vl[r] * c0 + v0[r] * c1 + v1[r] * c2;
        a1v.y += v0[r] * c0 + v1[r] * c1 + v2[r] * c2;
        a1v.z += v1[r] * c0 + v2[r] * c1 + v3[r] * c2;
        a1v.w += v2[r] * c0 + v3[r] * c1 + vr[r] * c2;
      }
      {  // out row h0+1 uses input rows kh+1
        const int r = kh + 1;
        b0v.x += vl[r] * a0 + v0[r] * a1 + v1[r] * a2;
        b0v.y += v0[r] * a0 + v1[r] * a1 + v2[r] * a2;
        b0v.z += v1[r] * a0 + v2[r] * a1 + v3[r] * a2;
        b0v.w += v2[r] * a0 + v3[r] * a1 + vr[r] * a2;
        b1v.x += vl[r] * c0 + v0[r] * c1 + v1[r] * c2;
        b1v.y += v0[r] * c0 + v1[r] * c1 + v2[r] * c2;
        b1v.z += v1[r] * c0 + v2[r] * c1 + v3[r] * c2;
        b1v.w += v2[r] * c0 + v3[r] * c1 + vr[r] * c2;
      }
    }
    wp0 += 9;
    wp1 += 9;
    xb += PLANE;
  }

  const size_t idx = ((size_t)b * HH + h0) * WW + w4;
  *(float4*)(off + idx) = a0v;                 // off_x row h0
  *(float4*)(off + idx + WW) = b0v;            // off_x row h0+1
  *(float4*)(off + NPIX + idx) = a1v;          // off_y row h0
  *(float4*)(off + NPIX + idx + WW) = b1v;     // off_y row h0+1
}

// ---------------------------------------------------------------------------
// Kernel B: bilinear zero-padded sample of 32 channels at (w+offx, h+offy).
// One thread per pixel; same XCD-band swizzle so each XCD gathers from a
// contiguous 256-row band (L2-resident per channel) and reads `off` written
// by the same XCD's L2. NT stores keep write-once output out of L2.
// ---------------------------------------------------------------------------
__global__ __launch_bounds__(256) void sample_kernel(
    const float* __restrict__ x, const float* __restrict__ off,
    float* __restrict__ out) {
  const int nb = gridDim.x;                       // 4096
  const int i  = blockIdx.x;
  const int j  = (i & 7) * (nb >> 3) + (i >> 3);  // XCD band swizzle
  const size_t tid = (size_t)j * 256 + threadIdx.x;

  const int w = (int)(tid & (WW - 1));
  const int h = (int)((tid >> 9) & (HH - 1));
  const int b = (int)(tid >> 18);

  const float ix = (float)w + off[tid];
  const float iy = (float)h + off[NPIX + tid];

  const float x0f = floorf(ix);
  const float y0f = floorf(iy);

  const float wx1 = ix - x0f;
  const float wx0 = 1.f - wx1;
  const float wy1 = iy - y0f;
  const float wy0 = 1.f - wy1;

  const bool vx0 = (x0f >= 0.f) && (x0f <= (float)(WW - 1));
  const bool vx1 = (x0f + 1.f >= 0.f) && (x0f + 1.f <= (float)(WW - 1));
  const bool vy0 = (y0f >= 0.f) && (y0f <= (float)(HH - 1));
  const bool vy1 = (y0f + 1.f >= 0.f) && (y0f + 1.f <= (float)(HH - 1));

  const int xi0 = (int)fminf(fmaxf(x0f, 0.f), (float)(WW - 1));
  const int xi1 = (int)fminf(fmaxf(x0f + 1.f, 0.f), (float)(WW - 1));
  const int yi0 = (int)fminf(fmaxf(y0f, 0.f), (float)(HH - 1));
  const int yi1 = (int)fminf(fmaxf(y0f + 1.f, 0.f), (float)(HH - 1));

  const float w00 = wy0 * wx0 * ((vy0 && vx0) ? 1.f : 0.f);
  const float w01 = wy0 * wx1 * ((vy0 && vx1) ? 1.f : 0.f);
  const float w10 = wy1 * wx0 * ((vy1 && vx0) ? 1.f : 0.f);
  const float w11 = wy1 * wx1 * ((vy1 && vx1) ? 1.f : 0.f);

  const int i00 = yi0 * WW + xi0;
  const int i01 = yi0 * WW + xi1;
  const int i10 = yi1 * WW + xi0;
  const int i11 = yi1 * WW + xi1;

  const float* xp = x + (size_t)b * CC * PLANE;
  float* ob = out + (size_t)b * CC * PLANE + (size_t)h * WW + w;

#pragma unroll 8
  for (int c = 0; c < CC; ++c) {
    const float v = w00 * xp[i00] + w01 * xp[i01] + w10 * xp[i10] + w11 * xp[i11];
    __builtin_nontemporal_store(v, ob);
    xp += PLANE;
    ob += PLANE;
  }
}

extern "C" void kernel_launch(void* const* d_in, const int* in_sizes, int n_in,
                              void* d_out, int out_size, void* d_ws, size_t ws_size,
                              hipStream_t stream) {
  const float* x     = (const float*)d_in[0];
  const float* w_off = (const float*)d_in[1];
  const float* b_off = (const float*)d_in[2];
  float* out = (float*)d_out;
  float* off = (float*)d_ws;  // 2 * B*H*W floats = 8 MB

  conv_off_kernel<<<512, 256, 0, stream>>>(x, w_off, b_off, off);

  const int nblk = (int)(NPIX / 256);  // 4096
  sample_kernel<<<nblk, 256, 0, stream>>>(x, off, out);
}